// Round 1
// baseline (491.980 us; speedup 1.0000x reference)
//
#include <hip/hip_runtime.h>
#include <math.h>

#define BB 4
#define NN 1024
#define HH 8
#define DD 64
#define BS 32
#define NB 32   // NN/BS
#define SS 16   // BLOCK_COUNTS

__device__ __forceinline__ float silu_f(float x) {
    return x / (1.f + __expf(-x));
}

// Block-mean compressed K/V: kc/vc layout [B][NB][H][D]
__global__ void cmp_mean_kernel(const float* __restrict__ pk,
                                const float* __restrict__ pv,
                                float* __restrict__ kc,
                                float* __restrict__ vc) {
    int idx = blockIdx.x;            // b*NB*HH + blk*HH + h
    int d = threadIdx.x;             // 64 threads = D
    int h = idx % HH;
    int tmp = idx / HH;
    int blk = tmp % NB;
    int b = tmp / NB;
    size_t base = (((size_t)b * NN + (size_t)blk * BS) * HH + h) * DD + d;
    float ks = 0.f, vs = 0.f;
    #pragma unroll
    for (int j = 0; j < BS; ++j) {
        ks += pk[base + (size_t)j * HH * DD];
        vs += pv[base + (size_t)j * HH * DD];
    }
    kc[(size_t)idx * DD + d] = ks * (1.f / BS);
    vc[(size_t)idx * DD + d] = vs * (1.f / BS);
}

// One wave per (valid token, head).
__global__ __launch_bounds__(256) void bsa_kernel(
    const float* __restrict__ pq, const float* __restrict__ pk,
    const float* __restrict__ pv, const float* __restrict__ kc,
    const float* __restrict__ vc, const float* __restrict__ gw,
    const int* __restrict__ gidx, float* __restrict__ out, int TH)
{
    __shared__ float q_lds[4][DD];
    int lane = threadIdx.x & 63;
    int w = threadIdx.x >> 6;
    int wave = blockIdx.x * 4 + w;
    bool valid = wave < TH;
    int wv = valid ? wave : 0;
    int t = wv >> 3;            // / HH
    int h = wv & (HH - 1);
    int g = gidx[t];
    int b = g >> 10;            // / NN
    int pos = g & (NN - 1);
    int q_blk = pos >> 5;

    size_t qbase = (((size_t)b * NN + pos) * HH + h) * DD;
    float qreg = pq[qbase + lane];
    q_lds[w][lane] = qreg;
    __syncthreads();            // single uniform sync; q_lds read-only after

    int blk = lane & 31;        // this lane's block / key slot
    int half = lane >> 5;       // which 32-wide d-half this lane reduces

    // ---- gates: sigmoid(q . gate_w[h,:,g]) for g in {0,1} ----
    float g0 = qreg * gw[(h * DD + lane) * 3 + 0];
    float g1 = qreg * gw[(h * DD + lane) * 3 + 1];
    #pragma unroll
    for (int off = 32; off; off >>= 1) {
        g0 += __shfl_xor(g0, off);
        g1 += __shfl_xor(g1, off);
    }
    float gate_cmp = 1.f / (1.f + __expf(-g0));
    float gate_slc = 1.f / (1.f + __expf(-g1));

    const float* qh = &q_lds[w][half * 32];

    // ---- compressed block scores: lane (blk, half) computes half-dot ----
    const float* kcrow = kc + (((size_t)b * NB + blk) * HH + h) * DD + half * 32;
    float part = 0.f;
    #pragma unroll
    for (int i = 0; i < 32; i += 4) {
        float4 qv = *(const float4*)(qh + i);
        float4 kv = *(const float4*)(kcrow + i);
        part += qv.x * kv.x + qv.y * kv.y + qv.z * kv.z + qv.w * kv.w;
    }
    float s_raw = (part + __shfl_xor(part, 32)) * 0.125f;   // scale = D^-0.5

    float p_cmp = (blk <= q_blk) ? silu_f(s_raw) : 0.f;

    // ---- o_cmp: lane d accumulates sum_j p[j] * v_cmp[j][d] ----
    float o_cmp = 0.f;
    const float* vcb = vc + (((size_t)b * NB) * HH + h) * DD + lane;
    for (int j = 0; j <= q_blk; ++j) {
        float pj = __shfl(p_cmp, j);
        o_cmp += pj * vcb[(size_t)j * HH * DD];
    }

    // ---- fused top-S selection + selected-block token attention ----
    float o_slc = 0.f;
    float sv = (blk <= q_blk) ? s_raw : -INFINITY;   // selection on RAW scores
    int nsel = min(q_blk + 1, SS);
    for (int it = 0; it < nsel; ++it) {
        // wave argmax with lower-index tie-break (matches jax top_k)
        float v = sv; int id = blk;
        #pragma unroll
        for (int off = 32; off; off >>= 1) {
            float v2 = __shfl_xor(v, off);
            int id2 = __shfl_xor(id, off);
            if (v2 > v || (v2 == v && id2 < id)) { v = v2; id = id2; }
        }
        if (blk == id) sv = -INFINITY;   // remove from candidates
        int sb = id;                      // wave-uniform selected block

        // token-level scores for block sb: lane (key=blk, half)
        int kpos = sb * BS + blk;
        const float* krow = pk + (((size_t)b * NN + kpos) * HH + h) * DD + half * 32;
        float pt = 0.f;
        #pragma unroll
        for (int i = 0; i < 32; i += 4) {
            float4 qv = *(const float4*)(qh + i);
            float4 kv = *(const float4*)(krow + i);
            pt += qv.x * kv.x + qv.y * kv.y + qv.z * kv.z + qv.w * kv.w;
        }
        float st = (pt + __shfl_xor(pt, 32)) * 0.125f;
        float ptok = (kpos <= pos) ? silu_f(st) : 0.f;   // token-causal

        // PV: lane d accumulates over the 32 keys of this block
        const float* vrow = pv + (((size_t)b * NN + (size_t)sb * BS) * HH + h) * DD + lane;
        #pragma unroll
        for (int j = 0; j < BS; ++j) {
            float pj = __shfl(ptok, j);
            o_slc += pj * vrow[(size_t)j * HH * DD];
        }
    }

    if (valid) {
        out[(size_t)wv * DD + lane] = o_cmp * gate_cmp + o_slc * gate_slc;
    }
}

extern "C" void kernel_launch(void* const* d_in, const int* in_sizes, int n_in,
                              void* d_out, int out_size, void* d_ws, size_t ws_size,
                              hipStream_t stream) {
    // inputs: 0 jagged_q, 1 jagged_k, 2 jagged_v, 3 jagged_u, 4 padded_q,
    //         5 padded_k, 6 padded_v, 7 x_offsets, 8 gate_w, 9 padding_mask,
    //         10 gather_idx
    const float* pq = (const float*)d_in[4];
    const float* pk = (const float*)d_in[5];
    const float* pv = (const float*)d_in[6];
    const float* gw = (const float*)d_in[8];
    const int* gidx = (const int*)d_in[10];
    float* out = (float*)d_out;

    int T = in_sizes[0] / (HH * DD);   // valid token count (3200)

    float* kc = (float*)d_ws;                                  // [B][NB][H][D]
    float* vc = kc + (size_t)BB * NB * HH * DD;                // [B][NB][H][D]

    cmp_mean_kernel<<<BB * NB * HH, DD, 0, stream>>>(pk, pv, kc, vc);

    int TH = T * HH;
    int blocks = (TH + 3) / 4;
    bsa_kernel<<<blocks, 256, 0, stream>>>(pq, pk, pv, kc, vc, gw, gidx, out, TH);
}

// Round 2
// 160.430 us; speedup vs baseline: 3.0666x; 3.0666x over previous
//
#include <hip/hip_runtime.h>
#include <math.h>
#include <stdint.h>

#define BB 4
#define NN 1024
#define HH 8
#define DD 64
#define BS 32
#define NB 32   // NN/BS
#define SS 16   // BLOCK_COUNTS

typedef __attribute__((ext_vector_type(8)))  short bf16x8;
typedef __attribute__((ext_vector_type(16))) float f32x16;
typedef __attribute__((ext_vector_type(2)))  int   int2v;

union FragU { bf16x8 h; uint32_t u[4]; };

#define ZERO16 {0.f,0.f,0.f,0.f,0.f,0.f,0.f,0.f,0.f,0.f,0.f,0.f,0.f,0.f,0.f,0.f}

__device__ __forceinline__ uint32_t cvt_pk_bf16(float lo, float hi) {
    uint32_t r;
    asm("v_cvt_pk_bf16_f32 %0, %1, %2" : "=v"(r) : "v"(lo), "v"(hi));
    return r;
}

__device__ __forceinline__ float silu_f(float x) {
    return __fdividef(x, 1.f + __expf(-x));
}

// Block-mean compressed K/V: kc/vc layout [B][NB][H][D] (f32)
__global__ void cmp_mean_kernel(const float* __restrict__ pk,
                                const float* __restrict__ pv,
                                float* __restrict__ kc,
                                float* __restrict__ vc) {
    int idx = blockIdx.x * 4 + (threadIdx.x >> 6);   // b*NB*HH + blk*HH + h
    int d = threadIdx.x & 63;
    int h = idx & 7;
    int blk = (idx >> 3) & 31;
    int b = idx >> 8;
    size_t base = (((size_t)b * NN + (size_t)blk * BS) * HH + h) * DD + d;
    float ks = 0.f, vs = 0.f;
    #pragma unroll
    for (int j = 0; j < BS; ++j) {
        ks += pk[base + (size_t)j * HH * DD];
        vs += pv[base + (size_t)j * HH * DD];
    }
    kc[(size_t)idx * DD + d] = ks * (1.f / BS);
    vc[(size_t)idx * DD + d] = vs * (1.f / BS);
}

// One workgroup (4 waves) per (b, h, q_block) tile of 32 queries.
__global__ __launch_bounds__(256, 3) void bsa_mfma_kernel(
    const float* __restrict__ pq, const float* __restrict__ pk,
    const float* __restrict__ pv, const float* __restrict__ kc,
    const float* __restrict__ vc, const float* __restrict__ gw,
    const int* __restrict__ xoff, float* __restrict__ out)
{
    __shared__ float qlds[32][64];                       // 8 KB
    __shared__ __align__(16) uint16_t pcmp[32][40];      // 2.5 KB, bf16, padded stride
    __shared__ uint32_t selmask[32];
    __shared__ float gateC[32], gateS[32];
    __shared__ float olds[5][32][64];                    // 40 KB: 4 attn slabs + 1 cmp slab

    const int tid = threadIdx.x;
    const int lane = tid & 63;
    const int w = tid >> 6;
    const int l31 = lane & 31;
    const int hi = lane >> 5;

    // inverse XCD swizzle: keep 128 consecutive tiles (4 (b,h) panels) per XCD
    const int bid = blockIdx.x;
    const int t_id = (bid & 7) * 128 + (bid >> 3);
    const int qb = t_id & 31;
    const int h = (t_id >> 5) & 7;
    const int b = t_id >> 8;

    const int off0 = xoff[b];
    const int len = xoff[b + 1] - off0;
    if (qb * BS >= len) return;                          // fully-padded tile (uniform)

    // ---- cooperative load of Q tile (f32) for selection/gates ----
    {
        int q = tid >> 3, part = (tid & 7) * 8;
        const float* src = pq + (((size_t)(b * NN + qb * BS + q)) * HH + h) * DD + part;
        *(float4*)&qlds[q][part] = *(const float4*)src;
        *(float4*)&qlds[q][part + 4] = *(const float4*)(src + 4);
    }

    // ---- Q B-fragments (bf16) direct from global: lane = query l31 ----
    FragU qf[4];
    {
        const float* qrow = pq + (((size_t)(b * NN + qb * BS + l31)) * HH + h) * DD;
        #pragma unroll
        for (int t = 0; t < 4; ++t) {
            const float* qp = qrow + t * 16 + hi * 8;
            float4 x = *(const float4*)qp;
            float4 y = *(const float4*)(qp + 4);
            qf[t].u[0] = cvt_pk_bf16(x.x, x.y);
            qf[t].u[1] = cvt_pk_bf16(x.z, x.w);
            qf[t].u[2] = cvt_pk_bf16(y.x, y.y);
            qf[t].u[3] = cvt_pk_bf16(y.z, y.w);
        }
    }

    // ---- compressed-K fragment for selection dots: lane = (blk=l31, half=hi) ----
    float4 kcv[8];
    {
        const float* kcrow = kc + (((size_t)(b * NB + l31)) * HH + h) * DD + hi * 32;
        #pragma unroll
        for (int i = 0; i < 8; ++i) kcv[i] = *(const float4*)(kcrow + i * 4);
    }

    __syncthreads();   // qlds ready

    // ---- selection + gates: wave w handles queries w*8 .. w*8+7 ----
    for (int j = 0; j < 8; ++j) {
        int q = w * 8 + j;
        const float* qv = qlds[q];
        // fp32 compressed score for this lane's block
        const float* qh = qv + hi * 32;
        float part = 0.f;
        #pragma unroll
        for (int i = 0; i < 8; ++i) {
            float4 qq = *(const float4*)(qh + i * 4);
            part += qq.x * kcv[i].x + qq.y * kcv[i].y + qq.z * kcv[i].z + qq.w * kcv[i].w;
        }
        float s = (part + __shfl_xor(part, 32)) * 0.125f;
        float p = (l31 <= qb) ? silu_f(s) : 0.f;
        if (lane < 32) {                                  // bf16 RNE store of p_cmp
            uint32_t fb = __float_as_uint(p);
            uint16_t bp = (uint16_t)((fb + 0x7fffu + ((fb >> 16) & 1u)) >> 16);
            pcmp[q][l31] = bp;
        }
        // top-16 mask (fp32 scores, index tie-break == jax.lax.top_k)
        uint32_t m;
        if (qb >= SS) {
            float vsel = (l31 <= qb) ? s : -INFINITY;
            int rank = 0;
            #pragma unroll
            for (int off = 1; off < 32; ++off) {
                float o = __shfl_xor(vsel, off);
                int oi = l31 ^ off;
                rank += (o > vsel || (o == vsel && oi < l31)) ? 1 : 0;
            }
            m = (uint32_t)(__ballot(rank < SS) & 0xffffffffu);
        } else {
            m = (1u << (qb + 1)) - 1u;
        }
        if (lane == 0) selmask[q] = m;
        // gates
        float qd = qv[lane];
        float g0 = qd * gw[(h * DD + lane) * 3 + 0];
        float g1 = qd * gw[(h * DD + lane) * 3 + 1];
        #pragma unroll
        for (int off = 32; off; off >>= 1) {
            g0 += __shfl_xor(g0, off);
            g1 += __shfl_xor(g1, off);
        }
        if (lane == 0) {
            gateC[q] = __frcp_rn(1.f + __expf(-g0));
            gateS[q] = __frcp_rn(1.f + __expf(-g1));
        }
    }

    __syncthreads();   // pcmp, selmask ready

    const uint32_t mymask = selmask[l31];
    f32x16 accO0 = ZERO16, accO1 = ZERO16;

    // ---- wave 3: compressed branch o_cmp = P_cmp · v_cmp via MFMA -> slab 4 ----
    if (w == 3) {
        f32x16 c0 = ZERO16, c1 = ZERO16;
        #pragma unroll
        for (int s = 0; s < 2; ++s) {
            FragU pa;
            pa.h = *(const bf16x8*)&pcmp[l31][s * 16 + hi * 8];
            const float* vbase = vc + (((size_t)(b * NB + s * 16 + hi * 8)) * HH + h) * DD + l31;
            #pragma unroll
            for (int dh = 0; dh < 2; ++dh) {
                FragU vb;
                #pragma unroll
                for (int jj = 0; jj < 4; ++jj) {
                    float a = vbase[(2 * jj) * 512 + dh * 32];
                    float c = vbase[(2 * jj + 1) * 512 + dh * 32];
                    vb.u[jj] = cvt_pk_bf16(a, c);
                }
                if (dh == 0) c0 = __builtin_amdgcn_mfma_f32_32x32x16_bf16(pa.h, vb.h, c0, 0, 0, 0);
                else         c1 = __builtin_amdgcn_mfma_f32_32x32x16_bf16(pa.h, vb.h, c1, 0, 0, 0);
            }
        }
        #pragma unroll
        for (int r = 0; r < 16; ++r) {
            int q = (r & 3) + 8 * (r >> 2) + 4 * hi;
            olds[4][q][l31] = c0[r];
            olds[4][q][32 + l31] = c1[r];
        }
    }

    // ---- main loop: wave w handles key-blocks kb = w, w+4, ... <= qb ----
    const int qpos = qb * BS + l31;
    for (int kb = w; kb <= qb; kb += 4) {
        // S^T = K_blk · Q^T  (4 mfma over d)
        f32x16 accS = ZERO16;
        const float* krow = pk + (((size_t)(b * NN + kb * BS + l31)) * HH + h) * DD;
        #pragma unroll
        for (int t = 0; t < 4; ++t) {
            const float* kp = krow + t * 16 + hi * 8;
            float4 x = *(const float4*)kp;
            float4 y = *(const float4*)(kp + 4);
            FragU kf;
            kf.u[0] = cvt_pk_bf16(x.x, x.y);
            kf.u[1] = cvt_pk_bf16(x.z, x.w);
            kf.u[2] = cvt_pk_bf16(y.x, y.y);
            kf.u[3] = cvt_pk_bf16(y.z, y.w);
            accS = __builtin_amdgcn_mfma_f32_32x32x16_bf16(kf.h, qf[t].h, accS, 0, 0, 0);
        }
        // mask + silu (lane holds q = l31; rows are keys)
        const bool selbit = (mymask >> kb) & 1;
        const bool notdiag = kb < qb;
        float pr[16];
        #pragma unroll
        for (int r = 0; r < 16; ++r) {
            int key = (r & 3) + 8 * (r >> 2) + 4 * hi;
            int kpos = kb * BS + key;
            float s = accS[r] * 0.125f;
            bool ok = selbit && (notdiag || kpos <= qpos);
            pr[r] = ok ? silu_f(s) : 0.f;
        }
        // P -> A-operand layout: cvt_pk pairs + permlane32 swaps (no LDS round-trip)
        uint32_t wv[8];
        #pragma unroll
        for (int i = 0; i < 8; ++i) wv[i] = cvt_pk_bf16(pr[2 * i], pr[2 * i + 1]);
        int2v e0 = __builtin_amdgcn_permlane32_swap(wv[0], wv[2], false, false);
        int2v e1 = __builtin_amdgcn_permlane32_swap(wv[1], wv[3], false, false);
        int2v e2 = __builtin_amdgcn_permlane32_swap(wv[4], wv[6], false, false);
        int2v e3 = __builtin_amdgcn_permlane32_swap(wv[5], wv[7], false, false);
        FragU a0, a1;
        a0.u[0] = e0[0]; a0.u[1] = e1[0]; a0.u[2] = e0[1]; a0.u[3] = e1[1];
        a1.u[0] = e2[0]; a1.u[1] = e3[0]; a1.u[2] = e2[1]; a1.u[3] = e3[1];
        // PV: O += P · V (V fragments direct from global, f32 -> bf16)
        #pragma unroll
        for (int s = 0; s < 2; ++s) {
            const float* vbase = pv + (((size_t)(b * NN + kb * BS + s * 16 + hi * 8)) * HH + h) * DD + l31;
            const FragU& pa = s ? a1 : a0;
            #pragma unroll
            for (int dh = 0; dh < 2; ++dh) {
                FragU vb;
                #pragma unroll
                for (int jj = 0; jj < 4; ++jj) {
                    float a = vbase[(2 * jj) * 512 + dh * 32];
                    float c = vbase[(2 * jj + 1) * 512 + dh * 32];
                    vb.u[jj] = cvt_pk_bf16(a, c);
                }
                if (dh == 0) accO0 = __builtin_amdgcn_mfma_f32_32x32x16_bf16(pa.h, vb.h, accO0, 0, 0, 0);
                else         accO1 = __builtin_amdgcn_mfma_f32_32x32x16_bf16(pa.h, vb.h, accO1, 0, 0, 0);
            }
        }
    }

    // ---- write per-wave partial slabs ----
    #pragma unroll
    for (int r = 0; r < 16; ++r) {
        int q = (r & 3) + 8 * (r >> 2) + 4 * hi;
        olds[w][q][l31] = accO0[r];
        olds[w][q][32 + l31] = accO1[r];
    }

    __syncthreads();

    // ---- reduce + gate + store (valid tokens only) ----
    {
        int q = tid >> 3, dpart = (tid & 7) * 8;
        int pos = qb * BS + q;
        if (pos < len) {
            float gc = gateC[q], gs = gateS[q];
            float res[8];
            #pragma unroll
            for (int dd = 0; dd < 8; ++dd) {
                int d = dpart + dd;
                float sum = olds[0][q][d] + olds[1][q][d] + olds[2][q][d] + olds[3][q][d];
                res[dd] = gc * olds[4][q][d] + gs * sum;
            }
            float* op = out + (((size_t)(off0 + pos)) * HH + h) * DD + dpart;
            *(float4*)op = make_float4(res[0], res[1], res[2], res[3]);
            *(float4*)(op + 4) = make_float4(res[4], res[5], res[6], res[7]);
        }
    }
}

extern "C" void kernel_launch(void* const* d_in, const int* in_sizes, int n_in,
                              void* d_out, int out_size, void* d_ws, size_t ws_size,
                              hipStream_t stream) {
    const float* pq = (const float*)d_in[4];
    const float* pk = (const float*)d_in[5];
    const float* pv = (const float*)d_in[6];
    const int* xoff = (const int*)d_in[7];
    const float* gw = (const float*)d_in[8];
    float* out = (float*)d_out;

    float* kc = (float*)d_ws;                                  // [B][NB][H][D]
    float* vc = kc + (size_t)BB * NB * HH * DD;                // [B][NB][H][D]

    cmp_mean_kernel<<<BB * NB * HH / 4, 256, 0, stream>>>(pk, pv, kc, vc);
    bsa_mfma_kernel<<<BB * HH * NB, 256, 0, stream>>>(pq, pk, pv, kc, vc, gw, xoff, out);
}